// Round 5
// baseline (10482.324 us; speedup 1.0000x reference)
//
#include <hip/hip_runtime.h>
#include <hip/hip_bf16.h>
#include <hip/hip_cooperative_groups.h>

namespace cg = cooperative_groups;

#define B_ 32
#define T_ 256
#define E_ 300
#define H_ 512
#define O_ 10
#define NSL 64   // h-slices per direction (8 h-indices each), 2*NSL blocks total

// ---------------- kernel 1: embedding gather + xg = x@W_ih^T + b_ih + b_hh --------
// xg layout: [dir][t][row 0..2047][b] as bf16, row = gate*512 + h
__global__ __launch_bounds__(256) void embed_xg_k(
    const int* __restrict__ tokens, const float* __restrict__ embed,
    const float* __restrict__ Wf, const float* __restrict__ bif, const float* __restrict__ bhf,
    const float* __restrict__ Wb, const float* __restrict__ bib, const float* __restrict__ bhb,
    __hip_bfloat16* __restrict__ xg)
{
  const int rt  = blockIdx.x;   // 16 row tiles of 128 rows
  const int t   = blockIdx.y;   // time
  const int dir = blockIdx.z;
  const float* __restrict__ W  = dir ? Wb : Wf;
  const float* __restrict__ bi = dir ? bib : bif;
  const float* __restrict__ bh = dir ? bhb : bhf;

  __shared__ int   tok_s[B_];
  __shared__ float x_lds[B_][301];   // pad 300->301: odd stride -> conflict-free
  const int tid = threadIdx.x;
  if (tid < B_) tok_s[tid] = tokens[tid * T_ + t];
  __syncthreads();
  for (int i = tid; i < B_ * E_; i += 256) {
    int b = i / E_, e = i - b * E_;
    x_lds[b][e] = embed[(size_t)tok_s[b] * E_ + e];
  }
  __syncthreads();

  const int rg = tid >> 5, b = tid & 31;
  const int rbase = rt * 128 + rg * 16;
  float acc[16];
  #pragma unroll
  for (int j = 0; j < 16; ++j) acc[j] = 0.f;
  for (int e = 0; e < E_; e += 4) {     // 300 % 4 == 0
    const float xv0 = x_lds[b][e + 0];
    const float xv1 = x_lds[b][e + 1];
    const float xv2 = x_lds[b][e + 2];
    const float xv3 = x_lds[b][e + 3];
    #pragma unroll
    for (int j = 0; j < 16; ++j) {
      const float4 w = *(const float4*)(W + (size_t)(rbase + j) * E_ + e);
      acc[j] += w.x * xv0 + w.y * xv1 + w.z * xv2 + w.w * xv3;
    }
  }
  const size_t obase = ((size_t)(dir * T_ + t) * 2048 + rbase) * B_ + b;
  #pragma unroll
  for (int j = 0; j < 16; ++j) {
    const float v = acc[j] + bi[rbase + j] + bh[rbase + j];
    xg[obase + (size_t)j * B_] = __float2bfloat16(v);
  }
}

// ---------------- kernel 2: cooperative bidirectional LSTM recurrence -------------
__device__ __forceinline__ float sigm(float x)    { return 1.f / (1.f + __expf(-x)); }
__device__ __forceinline__ float tanhfast(float x){ return 1.f - 2.f / (__expf(2.f * x) + 1.f); }

__global__ __launch_bounds__(256) void lstm_rec_k(
    const __hip_bfloat16* __restrict__ xg,
    const float* __restrict__ Whf, const float* __restrict__ Whb,
    float* __restrict__ hcomm, float* __restrict__ pooled,
    unsigned int* __restrict__ bar)
{
  const int dir = blockIdx.x & 1;   // even/odd -> XCD-segregated directions
  const int sl  = blockIdx.x >> 1;  // h-slice 0..63
  const int hs  = sl * 8;           // first h-index of this slice
  const float* __restrict__ Wh = dir ? Whb : Whf;   // [2048][512]

  extern __shared__ float lds[];
  float* h_lds = lds;               // [512][32] = 64 KiB (whole dynamic LDS)
  float* g_lds = lds;               // ALIASES h_lds[0:1024]; safe: barrier after matvec

  const int tid  = threadIdx.x;
  const int lane = tid & 63, wv = tid >> 6;     // wave = gate (i,f,g,o)
  const int mb   = lane & 31, hp = lane >> 5;   // matvec: batch lane, h-half
  const int eb   = tid & 31,  eh = tid >> 5;    // elementwise: batch, local h (0..7)

  const float* __restrict__ Wr0 = Wh + (size_t)(wv * H_ + hs + hp * 4) * H_;
  float c_st = 0.f, pm = 0.f;

  for (int s = 0; s < T_; ++s) {
    const int tt = dir ? (T_ - 1 - s) : s;
    // prefetch xg for this step
    float xgv[4];
    #pragma unroll
    for (int g = 0; g < 4; ++g)
      xgv[g] = __bfloat162float(xg[((size_t)(dir * T_ + tt) * 2048 + g * H_ + hs + eh) * B_ + eb]);

    float acc0 = 0.f, acc1 = 0.f, acc2 = 0.f, acc3 = 0.f;
    if (s > 0) {
      // stage h(s-1) [512][32] into LDS; safe: the step-(s-1) barrier's
      // release (wb) + acquire (inv) fences make producers' stores visible.
      const float4* src =
          (const float4*)(hcomm + (size_t)(dir * T_ + (s - 1)) * (H_ * B_));
      float4* dst = (float4*)h_lds;
      #pragma unroll
      for (int i = 0; i < 16; ++i)
        dst[tid + i * 256] = src[tid + i * 256];   // 4096 float4 = 16384 floats
      __syncthreads();
      // matvec: 4 rows (this gate, h = hs+hp*4+j) x 512, batch = mb
      for (int k = 0; k < H_; k += 4) {
        const float hv0 = h_lds[(k + 0) * B_ + mb];
        const float hv1 = h_lds[(k + 1) * B_ + mb];
        const float hv2 = h_lds[(k + 2) * B_ + mb];
        const float hv3 = h_lds[(k + 3) * B_ + mb];
        const float4 w0 = *(const float4*)(Wr0 + k);
        const float4 w1 = *(const float4*)(Wr0 + H_ + k);
        const float4 w2 = *(const float4*)(Wr0 + 2 * H_ + k);
        const float4 w3 = *(const float4*)(Wr0 + 3 * H_ + k);
        acc0 += w0.x * hv0 + w0.y * hv1 + w0.z * hv2 + w0.w * hv3;
        acc1 += w1.x * hv0 + w1.y * hv1 + w1.z * hv2 + w1.w * hv3;
        acc2 += w2.x * hv0 + w2.y * hv1 + w2.z * hv2 + w2.w * hv3;
        acc3 += w3.x * hv0 + w3.y * hv1 + w3.z * hv2 + w3.w * hv3;
      }
      __syncthreads();   // everyone done READING h_lds before g_lds (alias) writes
    }
    // exchange gates: g_lds[gate][hx][b]  (aliases h_lds[0:1024])
    g_lds[(wv * 8 + hp * 4 + 0) * 32 + mb] = acc0;
    g_lds[(wv * 8 + hp * 4 + 1) * 32 + mb] = acc1;
    g_lds[(wv * 8 + hp * 4 + 2) * 32 + mb] = acc2;
    g_lds[(wv * 8 + hp * 4 + 3) * 32 + mb] = acc3;
    __syncthreads();
    // elementwise LSTM cell for (b=eb, h=hs+eh)
    const float gi = g_lds[(0 * 8 + eh) * 32 + eb] + xgv[0];
    const float gf = g_lds[(1 * 8 + eh) * 32 + eb] + xgv[1];
    const float gg = g_lds[(2 * 8 + eh) * 32 + eb] + xgv[2];
    const float go = g_lds[(3 * 8 + eh) * 32 + eb] + xgv[3];
    c_st = sigm(gf) * c_st + sigm(gi) * tanhfast(gg);
    const float h = sigm(go) * tanhfast(c_st);
    pm = fmaxf(pm, h);   // == max over t of relu(h)
    hcomm[(size_t)(dir * T_ + s) * (H_ * B_) + (hs + eh) * B_ + eb] = h;

    // ---- hand-rolled per-direction barrier (grid.sync structure, tight spin) ----
    __threadfence();                         // release: wb own h stores to LLC
    __syncthreads();                         // all waves of this block fenced
    if (tid == 0) {
      unsigned int* c = bar + (size_t)dir * T_ + s;
      __hip_atomic_fetch_add(c, 1u, __ATOMIC_RELEASE, __HIP_MEMORY_SCOPE_AGENT);
      unsigned int v;
      do { v = __hip_atomic_load(c, __ATOMIC_RELAXED, __HIP_MEMORY_SCOPE_AGENT); }
      while (v < (unsigned)NSL);
    }
    __syncthreads();                         // block released by tid0
    __threadfence();                         // acquire: inv stale h lines
  }
  pooled[(size_t)eb * 1024 + dir * H_ + hs + eh] = pm;
}

// ---------------- kernel 3: hcomm [dir][s][k][b] -> rnn_out [t][b][dir*512+k] -----
__global__ __launch_bounds__(256) void finalize_k(
    const float* __restrict__ hcomm, float* __restrict__ rnn)
{
  const int t = blockIdx.x, dir = blockIdx.y;
  const int s = dir ? (T_ - 1 - t) : t;             // step that produced time t
  const float* __restrict__ src = hcomm + (size_t)(dir * T_ + s) * (H_ * B_);
  const int b = threadIdx.x >> 3, kq = threadIdx.x & 7;
  float* __restrict__ dst = rnn + ((size_t)t * B_ + b) * 1024 + dir * H_;
  #pragma unroll
  for (int j = 0; j < 16; ++j) {
    const int k = kq * 64 + j * 4;
    float4 v;
    v.x = src[(k + 0) * B_ + b];
    v.y = src[(k + 1) * B_ + b];
    v.z = src[(k + 2) * B_ + b];
    v.w = src[(k + 3) * B_ + b];
    *(float4*)(dst + k) = v;
  }
}

// ---------------- kernel 4: logits = pooled @ W_out^T + b_out ---------------------
__global__ __launch_bounds__(64) void logits_k(
    const float* __restrict__ pooled, const float* __restrict__ Wout,
    const float* __restrict__ bout, float* __restrict__ out)
{
  const int b = blockIdx.x, lane = threadIdx.x;
  float acc[O_];
  #pragma unroll
  for (int o = 0; o < O_; ++o) acc[o] = 0.f;
  for (int k = lane; k < 2 * H_; k += 64) {
    const float pv = pooled[(size_t)b * 1024 + k];
    #pragma unroll
    for (int o = 0; o < O_; ++o) acc[o] += pv * Wout[(size_t)o * 1024 + k];
  }
  #pragma unroll
  for (int o = 0; o < O_; ++o) {
    float v = acc[o];
    #pragma unroll
    for (int off = 32; off > 0; off >>= 1) v += __shfl_down(v, off);
    if (lane == 0) out[b * O_ + o] = v + bout[o];
  }
}

extern "C" void kernel_launch(void* const* d_in, const int* in_sizes, int n_in,
                              void* d_out, int out_size, void* d_ws, size_t ws_size,
                              hipStream_t stream)
{
  const int*   tokens = (const int*)d_in[0];
  const float* embed  = (const float*)d_in[1];
  const float* Wihf   = (const float*)d_in[2];
  const float* Whhf   = (const float*)d_in[3];
  const float* bihf   = (const float*)d_in[4];
  const float* bhhf   = (const float*)d_in[5];
  const float* Wihb   = (const float*)d_in[6];
  const float* Whhb   = (const float*)d_in[7];
  const float* bihb   = (const float*)d_in[8];
  const float* bhhb   = (const float*)d_in[9];
  const float* Wout   = (const float*)d_in[10];
  const float* bout   = (const float*)d_in[11];
  float* out = (float*)d_out;

  char* ws = (char*)d_ws;
  const size_t XG_BYTES = (size_t)2 * T_ * 2048 * B_ * 2;  // 67,108,864
  const size_t HC_BYTES = (size_t)2 * T_ * H_ * B_ * 4;    // 33,554,432
  const size_t PL_BYTES = (size_t)B_ * 1024 * 4;           //    131,072
  const size_t BA_BYTES = (size_t)2 * T_ * 4;              //      2,048
  if (ws_size < XG_BYTES + HC_BYTES + PL_BYTES + BA_BYTES) return;

  __hip_bfloat16* xg     = (__hip_bfloat16*)ws;
  float*          hcomm  = (float*)(ws + XG_BYTES);
  float*          pooled = (float*)(ws + XG_BYTES + HC_BYTES);
  unsigned int*   bar    = (unsigned int*)(ws + XG_BYTES + HC_BYTES + PL_BYTES);

  (void)hipMemsetAsync(bar, 0, BA_BYTES, stream);

  embed_xg_k<<<dim3(16, T_, 2), 256, 0, stream>>>(
      tokens, embed, Wihf, bihf, bhhf, Wihb, bihb, bhhb, xg);

  const int rec_lds = H_ * B_ * 4;   // 65,536 B (g_lds aliases h_lds)
  (void)hipFuncSetAttribute((const void*)lstm_rec_k,
                            hipFuncAttributeMaxDynamicSharedMemorySize, rec_lds);
  {
    const __hip_bfloat16* xg_c = xg;
    void* args[] = { (void*)&xg_c, (void*)&Whhf, (void*)&Whhb,
                     (void*)&hcomm, (void*)&pooled, (void*)&bar };
    (void)hipLaunchCooperativeKernel((const void*)lstm_rec_k,
                                     dim3(2 * NSL), dim3(256),
                                     args, rec_lds, stream);
  }

  finalize_k<<<dim3(T_, 2), 256, 0, stream>>>(hcomm, out + B_ * O_);
  logits_k<<<dim3(B_), 64, 0, stream>>>(pooled, Wout, bout, out);
}

// Round 8
// 9180.318 us; speedup vs baseline: 1.1418x; 1.1418x over previous
//
#include <hip/hip_runtime.h>
#include <hip/hip_bf16.h>

#define B_ 32
#define T_ 256
#define E_ 300
#define H_ 512
#define O_ 10
#define TEAM 32      // blocks per direction = CUs per XCD
#define THR 512      // threads per recurrence block (8 waves, 2/SIMD)
#define HPB 16       // h indices per block (512/32)
#define NBLK 512     // 2x oversubscribed so teams always fill

__device__ __forceinline__ float bf2f(unsigned short u) {
  unsigned v = ((unsigned)u) << 16; float f; __builtin_memcpy(&f, &v, 4); return f;
}

// ---------------- kernel 1: embedding gather + xg = x@W_ih^T + b_ih + b_hh --------
// xg layout: [dir][t][row 0..2047][b] as bf16, row = gate*512 + h
__global__ __launch_bounds__(256) void embed_xg_k(
    const int* __restrict__ tokens, const float* __restrict__ embed,
    const float* __restrict__ Wf, const float* __restrict__ bif, const float* __restrict__ bhf,
    const float* __restrict__ Wb, const float* __restrict__ bib, const float* __restrict__ bhb,
    __hip_bfloat16* __restrict__ xg)
{
  const int rt  = blockIdx.x;   // 16 row tiles of 128 rows
  const int t   = blockIdx.y;   // time
  const int dir = blockIdx.z;
  const float* __restrict__ W  = dir ? Wb : Wf;
  const float* __restrict__ bi = dir ? bib : bif;
  const float* __restrict__ bh = dir ? bhb : bhf;

  __shared__ int   tok_s[B_];
  __shared__ float x_lds[B_][301];   // pad 300->301: odd stride -> conflict-free
  const int tid = threadIdx.x;
  if (tid < B_) tok_s[tid] = tokens[tid * T_ + t];
  __syncthreads();
  for (int i = tid; i < B_ * E_; i += 256) {
    int b = i / E_, e = i - b * E_;
    x_lds[b][e] = embed[(size_t)tok_s[b] * E_ + e];
  }
  __syncthreads();

  const int rg = tid >> 5, b = tid & 31;
  const int rbase = rt * 128 + rg * 16;
  float acc[16];
  #pragma unroll
  for (int j = 0; j < 16; ++j) acc[j] = 0.f;
  for (int e = 0; e < E_; e += 4) {     // 300 % 4 == 0
    const float xv0 = x_lds[b][e + 0];
    const float xv1 = x_lds[b][e + 1];
    const float xv2 = x_lds[b][e + 2];
    const float xv3 = x_lds[b][e + 3];
    #pragma unroll
    for (int j = 0; j < 16; ++j) {
      const float4 w = *(const float4*)(W + (size_t)(rbase + j) * E_ + e);
      acc[j] += w.x * xv0 + w.y * xv1 + w.z * xv2 + w.w * xv3;
    }
  }
  const size_t obase = ((size_t)(dir * T_ + t) * 2048 + rbase) * B_ + b;
  #pragma unroll
  for (int j = 0; j < 16; ++j) {
    const float v = acc[j] + bi[rbase + j] + bh[rbase + j];
    xg[obase + (size_t)j * B_] = __float2bfloat16(v);
  }
}

// ---------------- kernel 2: XCD-local bidirectional LSTM recurrence ---------------
// 84KB LDS -> 1 block/CU. Blocks elect per-XCD ranks; XCD0 = dir0 team (32
// blocks), XCD1 = dir1 team, everyone else exits. All h communication stays
// inside one XCD's L2 (plain write-through stores + plain loads of fresh
// addresses). Mailboxes use agent-scope atomics (L1-proof, proven r0-r3).
// NO fences (buffer_wbl2 / buffer_inv) anywhere in the loop.
__device__ __forceinline__ float sigm(float x)    { return 1.f / (1.f + __expf(-x)); }
__device__ __forceinline__ float tanhfast(float x){ return 1.f - 2.f / (__expf(2.f * x) + 1.f); }

__global__ __launch_bounds__(THR) void lstm_rec_k(
    const __hip_bfloat16* __restrict__ xg,
    const float* __restrict__ Whf, const float* __restrict__ Whb,
    float* __restrict__ hcomm, float* __restrict__ pooled,
    unsigned int* __restrict__ slots, unsigned int* __restrict__ elect)
{
  unsigned xcd;
  asm volatile("s_getreg_b32 %0, hwreg(HW_REG_XCC_ID)" : "=s"(xcd));
  xcd &= 7u;

  __shared__ unsigned rank_s;
  if (threadIdx.x == 0)
    rank_s = __hip_atomic_fetch_add(&elect[xcd], 1u, __ATOMIC_RELAXED,
                                    __HIP_MEMORY_SCOPE_AGENT);
  __syncthreads();
  const unsigned rank = rank_s;
  if (xcd > 1u || rank >= TEAM) return;   // block-uniform exit (frees CU)
  const int dir = (int)xcd;

  const float* __restrict__ Wh = dir ? Whb : Whf;   // [2048][512]
  const int hs  = (int)rank * HPB;                  // this block's h range
  const int tid = threadIdx.x;
  const int b   = tid & 31;
  const int rq  = tid >> 5;                         // 0..15

  extern __shared__ float lds[];
  float* h_lds = lds;              // [512][32]  64 KB
  float* g_ex  = lds + H_ * B_;    // [64][32]    8 KB   (no aliasing)

  // rows r = rq*4 + j (j=0..3); gate g = r>>4; local h index ih = r&15
  const int r0 = rq * 4;
  const int g0_ = (r0 + 0) >> 4, i0_ = (r0 + 0) & 15;
  const int g1_ = (r0 + 1) >> 4, i1_ = (r0 + 1) & 15;
  const int g2_ = (r0 + 2) >> 4, i2_ = (r0 + 2) & 15;
  const int g3_ = (r0 + 3) >> 4, i3_ = (r0 + 3) & 15;
  const float* __restrict__ Wp0 = Wh + (size_t)(g0_ * H_ + hs + i0_) * H_;
  const float* __restrict__ Wp1 = Wh + (size_t)(g1_ * H_ + hs + i1_) * H_;
  const float* __restrict__ Wp2 = Wh + (size_t)(g2_ * H_ + hs + i2_) * H_;
  const float* __restrict__ Wp3 = Wh + (size_t)(g3_ * H_ + hs + i3_) * H_;
  const size_t xo0 = (size_t)(g0_ * H_ + hs + i0_) * B_ + b;
  const size_t xo1 = (size_t)(g1_ * H_ + hs + i1_) * B_ + b;
  const size_t xo2 = (size_t)(g2_ * H_ + hs + i2_) * B_ + b;
  const size_t xo3 = (size_t)(g3_ * H_ + hs + i3_) * B_ + b;
  const unsigned short* __restrict__ xgu = (const unsigned short*)xg;

  float c_st = 0.f, pm = 0.f;

  for (int s = 0; s < T_; ++s) {
    const int tt = dir ? (T_ - 1 - s) : s;
    const size_t xb = (size_t)(dir * T_ + tt) * 2048 * B_;
    // 1. xg prefetch (issues early; completes under the mailbox wait)
    float a0 = bf2f(__builtin_nontemporal_load(xgu + xb + xo0));
    float a1 = bf2f(__builtin_nontemporal_load(xgu + xb + xo1));
    float a2 = bf2f(__builtin_nontemporal_load(xgu + xb + xo2));
    float a3 = bf2f(__builtin_nontemporal_load(xgu + xb + xo3));

    if (s > 0) {
      // 2. mailbox wait: 32 lanes poll 32 per-rank slots with agent-scope
      //    atomic loads (cannot be served by L1; proven to propagate r0-r3)
      if (tid < 64) {
        unsigned v = 1u;
        const unsigned int* sp =
            slots + ((size_t)dir * T_ + (s - 1)) * TEAM + (tid & 31);
        int guard = 0;
        do {
          if (tid < 32)
            v = __hip_atomic_load(sp, __ATOMIC_RELAXED, __HIP_MEMORY_SCOPE_AGENT);
        } while (__ballot(v == 0u) != 0ull && ++guard < (1 << 22));
      }
      __syncthreads();
      // 3. stage h(s-1) [512][32] from (same-XCD) L2 into LDS
      const float4* src = (const float4*)(hcomm + (size_t)(dir * T_ + (s - 1)) * (H_ * B_));
      float4* dst = (float4*)h_lds;
      #pragma unroll
      for (int i = 0; i < 8; ++i)
        dst[tid + i * THR] = src[tid + i * THR];   // 4096 float4
      __syncthreads();
      // 4. matvec: 4 gate-rows x 512, batch = b
      for (int k = 0; k < H_; k += 4) {
        const float h0 = h_lds[(k + 0) * B_ + b];
        const float h1 = h_lds[(k + 1) * B_ + b];
        const float h2 = h_lds[(k + 2) * B_ + b];
        const float h3 = h_lds[(k + 3) * B_ + b];
        const float4 w0 = *(const float4*)(Wp0 + k);
        const float4 w1 = *(const float4*)(Wp1 + k);
        const float4 w2 = *(const float4*)(Wp2 + k);
        const float4 w3 = *(const float4*)(Wp3 + k);
        a0 += w0.x * h0 + w0.y * h1 + w0.z * h2 + w0.w * h3;
        a1 += w1.x * h0 + w1.y * h1 + w1.z * h2 + w1.w * h3;
        a2 += w2.x * h0 + w2.y * h1 + w2.z * h2 + w2.w * h3;
        a3 += w3.x * h0 + w3.y * h1 + w3.z * h2 + w3.w * h3;
      }
    }
    // 5. exchange gates through LDS: g_ex[r][b]
    g_ex[(r0 + 0) * B_ + b] = a0;
    g_ex[(r0 + 1) * B_ + b] = a1;
    g_ex[(r0 + 2) * B_ + b] = a2;
    g_ex[(r0 + 3) * B_ + b] = a3;
    __syncthreads();
    // 6. cell update for (b, h = hs + rq): gates at r = g*16 + rq
    const float Gi = g_ex[(0 * HPB + rq) * B_ + b];
    const float Gf = g_ex[(1 * HPB + rq) * B_ + b];
    const float Gg = g_ex[(2 * HPB + rq) * B_ + b];
    const float Go = g_ex[(3 * HPB + rq) * B_ + b];
    c_st = sigm(Gf) * c_st + sigm(Gi) * tanhfast(Gg);
    const float h = sigm(Go) * tanhfast(c_st);
    pm = fmaxf(pm, h);
    hcomm[(size_t)(dir * T_ + s) * (H_ * B_) + (hs + rq) * B_ + b] = h;
    // 7. publish: drain own write-through stores to (same-XCD) L2 block-wide,
    //    then agent-scope store to this rank's mailbox slot.
    asm volatile("s_waitcnt vmcnt(0)" ::: "memory");
    __syncthreads();
    if (tid == 0) {
      unsigned int* mp = slots + ((size_t)dir * T_ + s) * TEAM + rank;
      __hip_atomic_store(mp, 1u, __ATOMIC_RELAXED, __HIP_MEMORY_SCOPE_AGENT);
    }
  }
  pooled[(size_t)b * 1024 + dir * H_ + hs + rq] = pm;
}

// ---------------- kernel 3: hcomm [dir][s][k][b] -> rnn_out [t][b][dir*512+k] -----
__global__ __launch_bounds__(256) void finalize_k(
    const float* __restrict__ hcomm, float* __restrict__ rnn)
{
  const int t = blockIdx.x, dir = blockIdx.y;
  const int s = dir ? (T_ - 1 - t) : t;             // step that produced time t
  const float* __restrict__ src = hcomm + (size_t)(dir * T_ + s) * (H_ * B_);
  const int b = threadIdx.x >> 3, kq = threadIdx.x & 7;
  float* __restrict__ dst = rnn + ((size_t)t * B_ + b) * 1024 + dir * H_;
  #pragma unroll
  for (int j = 0; j < 16; ++j) {
    const int k = kq * 64 + j * 4;
    float4 v;
    v.x = src[(k + 0) * B_ + b];
    v.y = src[(k + 1) * B_ + b];
    v.z = src[(k + 2) * B_ + b];
    v.w = src[(k + 3) * B_ + b];
    *(float4*)(dst + k) = v;
  }
}

// ---------------- kernel 4: logits = pooled @ W_out^T + b_out ---------------------
__global__ __launch_bounds__(64) void logits_k(
    const float* __restrict__ pooled, const float* __restrict__ Wout,
    const float* __restrict__ bout, float* __restrict__ out)
{
  const int b = blockIdx.x, lane = threadIdx.x;
  float acc[O_];
  #pragma unroll
  for (int o = 0; o < O_; ++o) acc[o] = 0.f;
  for (int k = lane; k < 2 * H_; k += 64) {
    const float pv = pooled[(size_t)b * 1024 + k];
    #pragma unroll
    for (int o = 0; o < O_; ++o) acc[o] += pv * Wout[(size_t)o * 1024 + k];
  }
  #pragma unroll
  for (int o = 0; o < O_; ++o) {
    float v = acc[o];
    #pragma unroll
    for (int off = 32; off > 0; off >>= 1) v += __shfl_down(v, off);
    if (lane == 0) out[b * O_ + o] = v + bout[o];
  }
}

extern "C" void kernel_launch(void* const* d_in, const int* in_sizes, int n_in,
                              void* d_out, int out_size, void* d_ws, size_t ws_size,
                              hipStream_t stream)
{
  const int*   tokens = (const int*)d_in[0];
  const float* embed  = (const float*)d_in[1];
  const float* Wihf   = (const float*)d_in[2];
  const float* Whhf   = (const float*)d_in[3];
  const float* bihf   = (const float*)d_in[4];
  const float* bhhf   = (const float*)d_in[5];
  const float* Wihb   = (const float*)d_in[6];
  const float* Whhb   = (const float*)d_in[7];
  const float* bihb   = (const float*)d_in[8];
  const float* bhhb   = (const float*)d_in[9];
  const float* Wout   = (const float*)d_in[10];
  const float* bout   = (const float*)d_in[11];
  float* out = (float*)d_out;

  char* ws = (char*)d_ws;
  const size_t XG_BYTES = (size_t)2 * T_ * 2048 * B_ * 2;  // 67,108,864
  const size_t HC_BYTES = (size_t)2 * T_ * H_ * B_ * 4;    // 33,554,432
  const size_t PL_BYTES = (size_t)B_ * 1024 * 4;           //    131,072
  const size_t SL_BYTES = (size_t)2 * T_ * TEAM * 4;       //     65,536
  const size_t EL_BYTES = 8 * 4;                           //         32
  if (ws_size < XG_BYTES + HC_BYTES + PL_BYTES + SL_BYTES + EL_BYTES) return;

  __hip_bfloat16* xg     = (__hip_bfloat16*)ws;
  float*          hcomm  = (float*)(ws + XG_BYTES);
  float*          pooled = (float*)(ws + XG_BYTES + HC_BYTES);
  unsigned int*   slots  = (unsigned int*)(ws + XG_BYTES + HC_BYTES + PL_BYTES);
  unsigned int*   elect  = (unsigned int*)(ws + XG_BYTES + HC_BYTES + PL_BYTES + SL_BYTES);

  (void)hipMemsetAsync(slots, 0, SL_BYTES + EL_BYTES, stream);

  embed_xg_k<<<dim3(16, T_, 2), 256, 0, stream>>>(
      tokens, embed, Wihf, bihf, bhhf, Wihb, bihb, bhhb, xg);

  // 84 KB dynamic LDS: kernel uses 72 KB; padding forces exactly 1 block/CU.
  const int rec_lds = 86016;
  (void)hipFuncSetAttribute((const void*)lstm_rec_k,
                            hipFuncAttributeMaxDynamicSharedMemorySize, rec_lds);
  lstm_rec_k<<<dim3(NBLK), THR, rec_lds, stream>>>(xg, Whhf, Whhb, hcomm, pooled,
                                                   slots, elect);

  finalize_k<<<dim3(T_, 2), 256, 0, stream>>>(hcomm, out + B_ * O_);
  logits_k<<<dim3(B_), 64, 0, stream>>>(pooled, Wout, bout, out);
}

// Round 9
// 3993.500 us; speedup vs baseline: 2.6248x; 2.2988x over previous
//
#include <hip/hip_runtime.h>
#include <hip/hip_bf16.h>

#define B_ 32
#define T_ 256
#define E_ 300
#define H_ 512
#define O_ 10
#define TEAM 32      // blocks per direction = CUs per XCD
#define THR 512      // threads per recurrence block
#define HPB 16       // h indices per block (512/32)
#define NBLK 512     // 2x oversubscribed so teams always fill

typedef __attribute__((ext_vector_type(8))) short bf16x8;
typedef __attribute__((ext_vector_type(4))) float f32x4;

__device__ __forceinline__ float bf2f(unsigned short u) {
  unsigned v = ((unsigned)u) << 16; float f; __builtin_memcpy(&f, &v, 4); return f;
}
__device__ __forceinline__ short f2bf(float x) {   // RNE bf16 (finite inputs)
  unsigned u; __builtin_memcpy(&u, &x, 4);
  unsigned r = u + 0x7fffu + ((u >> 16) & 1u);
  return (short)(r >> 16);
}

// ---------------- kernel 1: embedding gather + xg = x@W_ih^T + b_ih + b_hh --------
// xg layout: [dir][t][row 0..2047][b] as bf16, row = gate*512 + h
__global__ __launch_bounds__(256) void embed_xg_k(
    const int* __restrict__ tokens, const float* __restrict__ embed,
    const float* __restrict__ Wf, const float* __restrict__ bif, const float* __restrict__ bhf,
    const float* __restrict__ Wb, const float* __restrict__ bib, const float* __restrict__ bhb,
    __hip_bfloat16* __restrict__ xg)
{
  const int rt  = blockIdx.x;   // 16 row tiles of 128 rows
  const int t   = blockIdx.y;   // time
  const int dir = blockIdx.z;
  const float* __restrict__ W  = dir ? Wb : Wf;
  const float* __restrict__ bi = dir ? bib : bif;
  const float* __restrict__ bh = dir ? bhb : bhf;

  __shared__ int   tok_s[B_];
  __shared__ float x_lds[B_][301];
  const int tid = threadIdx.x;
  if (tid < B_) tok_s[tid] = tokens[tid * T_ + t];
  __syncthreads();
  for (int i = tid; i < B_ * E_; i += 256) {
    int b = i / E_, e = i - b * E_;
    x_lds[b][e] = embed[(size_t)tok_s[b] * E_ + e];
  }
  __syncthreads();

  const int rg = tid >> 5, b = tid & 31;
  const int rbase = rt * 128 + rg * 16;
  float acc[16];
  #pragma unroll
  for (int j = 0; j < 16; ++j) acc[j] = 0.f;
  for (int e = 0; e < E_; e += 4) {
    const float xv0 = x_lds[b][e + 0];
    const float xv1 = x_lds[b][e + 1];
    const float xv2 = x_lds[b][e + 2];
    const float xv3 = x_lds[b][e + 3];
    #pragma unroll
    for (int j = 0; j < 16; ++j) {
      const float4 w = *(const float4*)(W + (size_t)(rbase + j) * E_ + e);
      acc[j] += w.x * xv0 + w.y * xv1 + w.z * xv2 + w.w * xv3;
    }
  }
  const size_t obase = ((size_t)(dir * T_ + t) * 2048 + rbase) * B_ + b;
  #pragma unroll
  for (int j = 0; j < 16; ++j) {
    const float v = acc[j] + bi[rbase + j] + bh[rbase + j];
    xg[obase + (size_t)j * B_] = __float2bfloat16(v);
  }
}

// ---------------- kernel 2: XCD-local MFMA LSTM recurrence ------------------------
// Structure proven in r8 (election, mailbox, plain-store h exchange). New engine:
// W_hh held in VGPRs as bf16 hi/lo A-fragments; gates via mfma_f32_16x16x32_bf16
// with 3 products (hi*hi + lo*hi + hi*lo) for fp32-grade accuracy.
// h exchanged as pre-swizzled bf16 hi/lo [b][k] (swz: byte ^= (b&7)<<4).
__device__ __forceinline__ float sigm(float x)    { return 1.f / (1.f + __expf(-x)); }
__device__ __forceinline__ float tanhfast(float x){ return 1.f - 2.f / (__expf(2.f * x) + 1.f); }

__global__ __launch_bounds__(THR) void lstm_rec_k(
    const __hip_bfloat16* __restrict__ xg,
    const float* __restrict__ Whf, const float* __restrict__ Whb,
    unsigned short* __restrict__ ht,   // [dir][s][hilo][32][512] bf16 pre-swizzled
    float* __restrict__ pooled,
    unsigned int* __restrict__ slots, unsigned int* __restrict__ elect)
{
  unsigned xcd;
  asm volatile("s_getreg_b32 %0, hwreg(HW_REG_XCC_ID)" : "=s"(xcd));
  xcd &= 7u;

  __shared__ unsigned rank_s;
  if (threadIdx.x == 0)
    rank_s = __hip_atomic_fetch_add(&elect[xcd], 1u, __ATOMIC_RELAXED,
                                    __HIP_MEMORY_SCOPE_AGENT);
  __syncthreads();
  const unsigned rank = rank_s;
  if (xcd > 1u || rank >= TEAM) return;   // block-uniform exit (frees CU)
  const int dir = (int)xcd;

  const float* __restrict__ Wh = dir ? Whb : Whf;   // [2048][512]
  const int hs  = (int)rank * HPB;
  const int tid = threadIdx.x;
  const int l   = tid & 63;            // MFMA lane
  const int wid = tid >> 6;            // 8 waves
  const int g   = wid & 3;             // gate (i,f,g,o)
  const int kh  = wid >> 2;            // k-half (0: k<256, 1: k>=256)
  const int hh  = tid & 15, bb = tid >> 4;   // cell-update role (h idx, batch)

  extern __shared__ char lds[];        // [0,64K): h bf16 hi|lo ; [64K,+17408): gp
  float* gp = (float*)(lds + 65536);   // [8 slot][32 b][17] fp32 gate partials

  // ---- A-fragment preload: this wave's 16 W rows x its 256-k half, bf16 hi/lo ---
  bf16x8 ahi[8], alo[8];
  {
    const int m = l & 15, q = l >> 4;
    const float* wrow = Wh + (size_t)(g * H_ + hs + m) * H_ + kh * 256 + q * 8;
    #pragma unroll
    for (int kt = 0; kt < 8; ++kt) {
      const float* wp = wrow + kt * 32;
      #pragma unroll
      for (int j = 0; j < 8; ++j) {
        const float w = wp[j];
        const short hi = f2bf(w);
        ahi[kt][j] = hi;
        alo[kt][j] = f2bf(w - bf2f((unsigned short)hi));
      }
    }
  }

  const unsigned short* __restrict__ xgu = (const unsigned short*)xg;
  const size_t xco = ((size_t)hs + hh) * B_ + bb;   // cell xg offset (per gate +512*32)

  float c_st = 0.f, pm = 0.f;

  for (int s = 0; s < T_; ++s) {
    const int tt = dir ? (T_ - 1 - s) : s;
    const size_t xb = (size_t)(dir * T_ + tt) * 2048 * B_;
    // xg prefetch for cell update (hides under poll/stage)
    float x0 = bf2f(__builtin_nontemporal_load(xgu + xb + 0 * H_ * B_ + xco));
    float x1 = bf2f(__builtin_nontemporal_load(xgu + xb + 1 * H_ * B_ + xco));
    float x2 = bf2f(__builtin_nontemporal_load(xgu + xb + 2 * H_ * B_ + xco));
    float x3 = bf2f(__builtin_nontemporal_load(xgu + xb + 3 * H_ * B_ + xco));

    if (s > 0) {
      // mailbox wait (r8-proven agent-scope atomic poll)
      if (tid < 64) {
        unsigned v = 1u;
        const unsigned int* sp =
            slots + ((size_t)dir * T_ + (s - 1)) * TEAM + (tid & 31);
        int guard = 0;
        do {
          if (tid < 32)
            v = __hip_atomic_load(sp, __ATOMIC_RELAXED, __HIP_MEMORY_SCOPE_AGENT);
        } while (__ballot(v == 0u) != 0ull && ++guard < (1 << 22));
      }
      __syncthreads();
      // stage h(s-1) hi+lo (64 KB, already swizzled) linearly into LDS
      {
        const float4* src = (const float4*)(ht + (size_t)(dir * T_ + (s - 1)) * 32768);
        float4* dst = (float4*)lds;
        #pragma unroll
        for (int i = 0; i < 8; ++i)
          dst[tid + i * THR] = src[tid + i * THR];
      }
      __syncthreads();
      // MFMA: gates[g*16+hs.. ][b] partial over this k-half
      f32x4 acc0 = {0.f, 0.f, 0.f, 0.f}, acc1 = {0.f, 0.f, 0.f, 0.f};
      {
        const int n0 = l & 15;
        const int swz = (n0 & 7) << 4;
        const int kb = kh * 512 + (l >> 4) * 16;   // byte offset of this lane's k
        #pragma unroll
        for (int kt = 0; kt < 8; ++kt) {
          const int ko = kb + kt * 64;
          const char* p0 = lds + (((n0      ) * 1024 + ko) ^ swz);
          const char* p1 = lds + (((n0 + 16 ) * 1024 + ko) ^ swz);
          bf16x8 b0h = *(const bf16x8*)(p0);
          bf16x8 b0l = *(const bf16x8*)(p0 + 32768);
          bf16x8 b1h = *(const bf16x8*)(p1);
          bf16x8 b1l = *(const bf16x8*)(p1 + 32768);
          acc0 = __builtin_amdgcn_mfma_f32_16x16x32_bf16(ahi[kt], b0h, acc0, 0, 0, 0);
          acc0 = __builtin_amdgcn_mfma_f32_16x16x32_bf16(alo[kt], b0h, acc0, 0, 0, 0);
          acc0 = __builtin_amdgcn_mfma_f32_16x16x32_bf16(ahi[kt], b0l, acc0, 0, 0, 0);
          acc1 = __builtin_amdgcn_mfma_f32_16x16x32_bf16(ahi[kt], b1h, acc1, 0, 0, 0);
          acc1 = __builtin_amdgcn_mfma_f32_16x16x32_bf16(alo[kt], b1h, acc1, 0, 0, 0);
          acc1 = __builtin_amdgcn_mfma_f32_16x16x32_bf16(ahi[kt], b1l, acc1, 0, 0, 0);
        }
      }
      // write gate partials: C layout col=lane&15 (batch), row=(lane>>4)*4+r (h)
      {
        const int slot = (kh * 4 + g) * 32;
        const int rowb = (l >> 4) * 4;
        #pragma unroll
        for (int r = 0; r < 4; ++r) {
          gp[(slot + (l & 15)     ) * 17 + rowb + r] = acc0[r];
          gp[(slot + 16 + (l & 15)) * 17 + rowb + r] = acc1[r];
        }
      }
      __syncthreads();
    }

    // ---- cell update for (h = hs+hh, batch bb) ----
    float Gi = x0, Gf = x1, Gg = x2, Go = x3;
    if (s > 0) {
      Gi += gp[(0 * 32 + bb) * 17 + hh] + gp[(4 * 32 + bb) * 17 + hh];
      Gf += gp[(1 * 32 + bb) * 17 + hh] + gp[(5 * 32 + bb) * 17 + hh];
      Gg += gp[(2 * 32 + bb) * 17 + hh] + gp[(6 * 32 + bb) * 17 + hh];
      Go += gp[(3 * 32 + bb) * 17 + hh] + gp[(7 * 32 + bb) * 17 + hh];
    }
    c_st = sigm(Gf) * c_st + sigm(Gi) * tanhfast(Gg);
    const float h = sigm(Go) * tanhfast(c_st);
    pm = fmaxf(pm, h);
    // publish h as bf16 hi/lo, pre-swizzled [b][k] (byte ^= (b&7)<<4)
    {
      const short hi = f2bf(h);
      const short lo = f2bf(h - bf2f((unsigned short)hi));
      char* base = (char*)(ht + (size_t)(dir * T_ + s) * 32768);
      const unsigned off = (unsigned)((bb * 1024 + (hs + hh) * 2) ^ ((bb & 7) << 4));
      *(unsigned short*)(base + off)         = (unsigned short)hi;
      *(unsigned short*)(base + 32768 + off) = (unsigned short)lo;
    }
    asm volatile("s_waitcnt vmcnt(0)" ::: "memory");
    __syncthreads();
    if (tid == 0) {
      unsigned int* mp = slots + ((size_t)dir * T_ + s) * TEAM + rank;
      __hip_atomic_store(mp, 1u, __ATOMIC_RELAXED, __HIP_MEMORY_SCOPE_AGENT);
    }
  }
  pooled[(size_t)bb * 1024 + dir * H_ + hs + hh] = pm;
}

// ---------------- kernel 3: ht bf16 hi/lo -> rnn_out [t][b][dir*512+k] fp32 -------
__global__ __launch_bounds__(256) void finalize_k(
    const unsigned short* __restrict__ ht, float* __restrict__ rnn)
{
  const int t = blockIdx.x, dir = blockIdx.y;
  const int s = dir ? (T_ - 1 - t) : t;
  const char* base = (const char*)(ht + (size_t)(dir * T_ + s) * 32768);
  const int b = threadIdx.x >> 3, c = threadIdx.x & 7;
  float* __restrict__ dst = rnn + ((size_t)t * B_ + b) * 1024 + dir * H_;
  #pragma unroll
  for (int j = 0; j < 8; ++j) {
    const int k0 = (c * 8 + j) * 8;
    const unsigned off = (unsigned)((b * 1024 + k0 * 2) ^ ((b & 7) << 4));
    bf16x8 hi = *(const bf16x8*)(base + off);
    bf16x8 lo = *(const bf16x8*)(base + 32768 + off);
    float4 o0, o1;
    o0.x = bf2f((unsigned short)hi[0]) + bf2f((unsigned short)lo[0]);
    o0.y = bf2f((unsigned short)hi[1]) + bf2f((unsigned short)lo[1]);
    o0.z = bf2f((unsigned short)hi[2]) + bf2f((unsigned short)lo[2]);
    o0.w = bf2f((unsigned short)hi[3]) + bf2f((unsigned short)lo[3]);
    o1.x = bf2f((unsigned short)hi[4]) + bf2f((unsigned short)lo[4]);
    o1.y = bf2f((unsigned short)hi[5]) + bf2f((unsigned short)lo[5]);
    o1.z = bf2f((unsigned short)hi[6]) + bf2f((unsigned short)lo[6]);
    o1.w = bf2f((unsigned short)hi[7]) + bf2f((unsigned short)lo[7]);
    *(float4*)(dst + k0)     = o0;
    *(float4*)(dst + k0 + 4) = o1;
  }
}

// ---------------- kernel 4: logits = pooled @ W_out^T + b_out ---------------------
__global__ __launch_bounds__(64) void logits_k(
    const float* __restrict__ pooled, const float* __restrict__ Wout,
    const float* __restrict__ bout, float* __restrict__ out)
{
  const int b = blockIdx.x, lane = threadIdx.x;
  float acc[O_];
  #pragma unroll
  for (int o = 0; o < O_; ++o) acc[o] = 0.f;
  for (int k = lane; k < 2 * H_; k += 64) {
    const float pv = pooled[(size_t)b * 1024 + k];
    #pragma unroll
    for (int o = 0; o < O_; ++o) acc[o] += pv * Wout[(size_t)o * 1024 + k];
  }
  #pragma unroll
  for (int o = 0; o < O_; ++o) {
    float v = acc[o];
    #pragma unroll
    for (int off = 32; off > 0; off >>= 1) v += __shfl_down(v, off);
    if (lane == 0) out[b * O_ + o] = v + bout[o];
  }
}

extern "C" void kernel_launch(void* const* d_in, const int* in_sizes, int n_in,
                              void* d_out, int out_size, void* d_ws, size_t ws_size,
                              hipStream_t stream)
{
  const int*   tokens = (const int*)d_in[0];
  const float* embed  = (const float*)d_in[1];
  const float* Wihf   = (const float*)d_in[2];
  const float* Whhf   = (const float*)d_in[3];
  const float* bihf   = (const float*)d_in[4];
  const float* bhhf   = (const float*)d_in[5];
  const float* Wihb   = (const float*)d_in[6];
  const float* Whhb   = (const float*)d_in[7];
  const float* bihb   = (const float*)d_in[8];
  const float* bhhb   = (const float*)d_in[9];
  const float* Wout   = (const float*)d_in[10];
  const float* bout   = (const float*)d_in[11];
  float* out = (float*)d_out;

  char* ws = (char*)d_ws;
  const size_t XG_BYTES = (size_t)2 * T_ * 2048 * B_ * 2;       // 67,108,864
  const size_t HT_BYTES = (size_t)2 * T_ * 2 * B_ * H_ * 2;     // 33,554,432
  const size_t PL_BYTES = (size_t)B_ * 1024 * 4;                //    131,072
  const size_t SL_BYTES = (size_t)2 * T_ * TEAM * 4;            //     65,536
  const size_t EL_BYTES = 8 * 4;                                //         32
  if (ws_size < XG_BYTES + HT_BYTES + PL_BYTES + SL_BYTES + EL_BYTES) return;

  __hip_bfloat16* xg     = (__hip_bfloat16*)ws;
  unsigned short* ht     = (unsigned short*)(ws + XG_BYTES);
  float*          pooled = (float*)(ws + XG_BYTES + HT_BYTES);
  unsigned int*   slots  = (unsigned int*)(ws + XG_BYTES + HT_BYTES + PL_BYTES);
  unsigned int*   elect  = (unsigned int*)(ws + XG_BYTES + HT_BYTES + PL_BYTES + SL_BYTES);

  (void)hipMemsetAsync(slots, 0, SL_BYTES + EL_BYTES, stream);

  embed_xg_k<<<dim3(16, T_, 2), 256, 0, stream>>>(
      tokens, embed, Wihf, bihf, bhhf, Wihb, bihb, bhhb, xg);

  // 82,944 B dynamic LDS (64K h + 17,408 gp); 2x82944 > 160 KB -> 1 block/CU.
  const int rec_lds = 82944;
  (void)hipFuncSetAttribute((const void*)lstm_rec_k,
                            hipFuncAttributeMaxDynamicSharedMemorySize, rec_lds);
  lstm_rec_k<<<dim3(NBLK), THR, rec_lds, stream>>>(xg, Whhf, Whhb, ht, pooled,
                                                   slots, elect);

  finalize_k<<<dim3(T_, 2), 256, 0, stream>>>(ht, out + B_ * O_);
  logits_k<<<dim3(B_), 64, 0, stream>>>(pooled, Wout, bout, out);
}

// Round 10
// 3978.804 us; speedup vs baseline: 2.6345x; 1.0037x over previous
//
#include <hip/hip_runtime.h>
#include <hip/hip_bf16.h>

#define B_ 32
#define T_ 256
#define E_ 300
#define H_ 512
#define O_ 10
#define TEAM 32      // blocks per direction = CUs per XCD
#define THR 512      // threads per recurrence block
#define HPB 16       // h indices per block (512/32)
#define NBLK 512     // 2x oversubscribed so teams always fill

typedef __attribute__((ext_vector_type(8))) short bf16x8;
typedef __attribute__((ext_vector_type(4))) float f32x4;

__device__ __forceinline__ float bf2f(unsigned short u) {
  unsigned v = ((unsigned)u) << 16; float f; __builtin_memcpy(&f, &v, 4); return f;
}
__device__ __forceinline__ short f2bf(float x) {   // RNE bf16 (finite inputs)
  unsigned u; __builtin_memcpy(&u, &x, 4);
  unsigned r = u + 0x7fffu + ((u >> 16) & 1u);
  return (short)(r >> 16);
}

// ---------------- kernel 1: embedding gather + xg = x@W_ih^T + b_ih + b_hh --------
// xg layout: [dir][t][row 0..2047][b] as bf16, row = gate*512 + h
__global__ __launch_bounds__(256) void embed_xg_k(
    const int* __restrict__ tokens, const float* __restrict__ embed,
    const float* __restrict__ Wf, const float* __restrict__ bif, const float* __restrict__ bhf,
    const float* __restrict__ Wb, const float* __restrict__ bib, const float* __restrict__ bhb,
    __hip_bfloat16* __restrict__ xg)
{
  const int rt  = blockIdx.x;   // 16 row tiles of 128 rows
  const int t   = blockIdx.y;   // time
  const int dir = blockIdx.z;
  const float* __restrict__ W  = dir ? Wb : Wf;
  const float* __restrict__ bi = dir ? bib : bif;
  const float* __restrict__ bh = dir ? bhb : bhf;

  __shared__ int   tok_s[B_];
  __shared__ float x_lds[B_][301];
  const int tid = threadIdx.x;
  if (tid < B_) tok_s[tid] = tokens[tid * T_ + t];
  __syncthreads();
  for (int i = tid; i < B_ * E_; i += 256) {
    int b = i / E_, e = i - b * E_;
    x_lds[b][e] = embed[(size_t)tok_s[b] * E_ + e];
  }
  __syncthreads();

  const int rg = tid >> 5, b = tid & 31;
  const int rbase = rt * 128 + rg * 16;
  float acc[16];
  #pragma unroll
  for (int j = 0; j < 16; ++j) acc[j] = 0.f;
  for (int e = 0; e < E_; e += 4) {
    const float xv0 = x_lds[b][e + 0];
    const float xv1 = x_lds[b][e + 1];
    const float xv2 = x_lds[b][e + 2];
    const float xv3 = x_lds[b][e + 3];
    #pragma unroll
    for (int j = 0; j < 16; ++j) {
      const float4 w = *(const float4*)(W + (size_t)(rbase + j) * E_ + e);
      acc[j] += w.x * xv0 + w.y * xv1 + w.z * xv2 + w.w * xv3;
    }
  }
  const size_t obase = ((size_t)(dir * T_ + t) * 2048 + rbase) * B_ + b;
  #pragma unroll
  for (int j = 0; j < 16; ++j) {
    const float v = acc[j] + bi[rbase + j] + bh[rbase + j];
    xg[obase + (size_t)j * B_] = __float2bfloat16(v);
  }
}

// ---------------- kernel 2: XCD-local MFMA LSTM recurrence ------------------------
// r9 engine (W_hh in VGPRs as bf16 hi/lo, mfma_f32_16x16x32_bf16 x3 products,
// swizzled bf16 hi/lo h exchange through same-XCD L2). Barrier v2: ONE counter
// per (dir,step); arrive = tid0 agent fetch_add; poll = tid0-only agent load.
__device__ __forceinline__ float sigm(float x)    { return 1.f / (1.f + __expf(-x)); }
__device__ __forceinline__ float tanhfast(float x){ return 1.f - 2.f / (__expf(2.f * x) + 1.f); }

__global__ __launch_bounds__(THR) void lstm_rec_k(
    const __hip_bfloat16* __restrict__ xg,
    const float* __restrict__ Whf, const float* __restrict__ Whb,
    unsigned short* __restrict__ ht,   // [dir][s][hilo][32][512] bf16 pre-swizzled
    float* __restrict__ pooled,
    unsigned int* __restrict__ cnt, unsigned int* __restrict__ elect)
{
  unsigned xcd;
  asm volatile("s_getreg_b32 %0, hwreg(HW_REG_XCC_ID)" : "=s"(xcd));
  xcd &= 7u;

  __shared__ unsigned rank_s;
  if (threadIdx.x == 0)
    rank_s = __hip_atomic_fetch_add(&elect[xcd], 1u, __ATOMIC_RELAXED,
                                    __HIP_MEMORY_SCOPE_AGENT);
  __syncthreads();
  const unsigned rank = rank_s;
  if (xcd > 1u || rank >= TEAM) return;   // block-uniform exit (frees CU)
  const int dir = (int)xcd;

  const float* __restrict__ Wh = dir ? Whb : Whf;   // [2048][512]
  const int hs  = (int)rank * HPB;
  const int tid = threadIdx.x;
  const int l   = tid & 63;            // MFMA lane
  const int wid = tid >> 6;            // 8 waves
  const int g   = wid & 3;             // gate (i,f,g,o)
  const int kh  = wid >> 2;            // k-half (0: k<256, 1: k>=256)
  const int hh  = tid & 15, bb = tid >> 4;   // cell-update role (h idx, batch)

  extern __shared__ char lds[];        // [0,64K): h bf16 hi|lo ; [64K,+17408): gp
  float* gp = (float*)(lds + 65536);   // [8 slot][32 b][17] fp32 gate partials

  // ---- A-fragment preload: this wave's 16 W rows x its 256-k half, bf16 hi/lo ---
  bf16x8 ahi[8], alo[8];
  {
    const int m = l & 15, q = l >> 4;
    const float* wrow = Wh + (size_t)(g * H_ + hs + m) * H_ + kh * 256 + q * 8;
    #pragma unroll
    for (int kt = 0; kt < 8; ++kt) {
      const float* wp = wrow + kt * 32;
      #pragma unroll
      for (int j = 0; j < 8; ++j) {
        const float w = wp[j];
        const short hi = f2bf(w);
        ahi[kt][j] = hi;
        alo[kt][j] = f2bf(w - bf2f((unsigned short)hi));
      }
    }
  }

  const unsigned short* __restrict__ xgu = (const unsigned short*)xg;
  const size_t xco = ((size_t)hs + hh) * B_ + bb;   // cell xg offset (per gate +512*32)
  unsigned int* __restrict__ mycnt = cnt + (size_t)dir * T_;

  float c_st = 0.f, pm = 0.f;

  for (int s = 0; s < T_; ++s) {
    const int tt = dir ? (T_ - 1 - s) : s;
    const size_t xb = (size_t)(dir * T_ + tt) * 2048 * B_;
    // xg prefetch for cell update (hides under poll/stage)
    float x0 = bf2f(__builtin_nontemporal_load(xgu + xb + 0 * H_ * B_ + xco));
    float x1 = bf2f(__builtin_nontemporal_load(xgu + xb + 1 * H_ * B_ + xco));
    float x2 = bf2f(__builtin_nontemporal_load(xgu + xb + 2 * H_ * B_ + xco));
    float x3 = bf2f(__builtin_nontemporal_load(xgu + xb + 3 * H_ * B_ + xco));

    if (s > 0) {
      // barrier v2 poll: tid0 spins on one counter (agent-scope, L1-proof)
      if (tid == 0) {
        const unsigned int* cp = mycnt + (s - 1);
        unsigned v; int guard = 0;
        do { v = __hip_atomic_load(cp, __ATOMIC_RELAXED, __HIP_MEMORY_SCOPE_AGENT); }
        while (v < (unsigned)TEAM && ++guard < (1 << 22));
      }
      __syncthreads();
      // stage h(s-1) hi+lo (64 KB, already swizzled) linearly into LDS
      {
        const float4* src = (const float4*)(ht + (size_t)(dir * T_ + (s - 1)) * 32768);
        float4* dst = (float4*)lds;
        #pragma unroll
        for (int i = 0; i < 8; ++i)
          dst[tid + i * THR] = src[tid + i * THR];
      }
      __syncthreads();
      // MFMA: gates[g*16+hs.. ][b] partial over this k-half
      f32x4 acc0 = {0.f, 0.f, 0.f, 0.f}, acc1 = {0.f, 0.f, 0.f, 0.f};
      {
        const int n0 = l & 15;
        const int swz = (n0 & 7) << 4;
        const int kb = kh * 512 + (l >> 4) * 16;   // byte offset of this lane's k
        #pragma unroll
        for (int kt = 0; kt < 8; ++kt) {
          const int ko = kb + kt * 64;
          const char* p0 = lds + (((n0      ) * 1024 + ko) ^ swz);
          const char* p1 = lds + (((n0 + 16 ) * 1024 + ko) ^ swz);
          bf16x8 b0h = *(const bf16x8*)(p0);
          bf16x8 b0l = *(const bf16x8*)(p0 + 32768);
          bf16x8 b1h = *(const bf16x8*)(p1);
          bf16x8 b1l = *(const bf16x8*)(p1 + 32768);
          acc0 = __builtin_amdgcn_mfma_f32_16x16x32_bf16(ahi[kt], b0h, acc0, 0, 0, 0);
          acc0 = __builtin_amdgcn_mfma_f32_16x16x32_bf16(alo[kt], b0h, acc0, 0, 0, 0);
          acc0 = __builtin_amdgcn_mfma_f32_16x16x32_bf16(ahi[kt], b0l, acc0, 0, 0, 0);
          acc1 = __builtin_amdgcn_mfma_f32_16x16x32_bf16(ahi[kt], b1h, acc1, 0, 0, 0);
          acc1 = __builtin_amdgcn_mfma_f32_16x16x32_bf16(alo[kt], b1h, acc1, 0, 0, 0);
          acc1 = __builtin_amdgcn_mfma_f32_16x16x32_bf16(ahi[kt], b1l, acc1, 0, 0, 0);
        }
      }
      // write gate partials: C layout col=lane&15 (batch), row=(lane>>4)*4+r (h)
      {
        const int slot = (kh * 4 + g) * 32;
        const int rowb = (l >> 4) * 4;
        #pragma unroll
        for (int r = 0; r < 4; ++r) {
          gp[(slot + (l & 15)     ) * 17 + rowb + r] = acc0[r];
          gp[(slot + 16 + (l & 15)) * 17 + rowb + r] = acc1[r];
        }
      }
      __syncthreads();
    }

    // ---- cell update for (h = hs+hh, batch bb) ----
    float Gi = x0, Gf = x1, Gg = x2, Go = x3;
    if (s > 0) {
      Gi += gp[(0 * 32 + bb) * 17 + hh] + gp[(4 * 32 + bb) * 17 + hh];
      Gf += gp[(1 * 32 + bb) * 17 + hh] + gp[(5 * 32 + bb) * 17 + hh];
      Gg += gp[(2 * 32 + bb) * 17 + hh] + gp[(6 * 32 + bb) * 17 + hh];
      Go += gp[(3 * 32 + bb) * 17 + hh] + gp[(7 * 32 + bb) * 17 + hh];
    }
    c_st = sigm(Gf) * c_st + sigm(Gi) * tanhfast(Gg);
    const float h = sigm(Go) * tanhfast(c_st);
    pm = fmaxf(pm, h);
    // publish h as bf16 hi/lo, pre-swizzled [b][k] (byte ^= (b&7)<<4)
    {
      const short hi = f2bf(h);
      const short lo = f2bf(h - bf2f((unsigned short)hi));
      char* base = (char*)(ht + (size_t)(dir * T_ + s) * 32768);
      const unsigned off = (unsigned)((bb * 1024 + (hs + hh) * 2) ^ ((bb & 7) << 4));
      *(unsigned short*)(base + off)         = (unsigned short)hi;
      *(unsigned short*)(base + 32768 + off) = (unsigned short)lo;
    }
    asm volatile("s_waitcnt vmcnt(0)" ::: "memory");
    __syncthreads();
    if (tid == 0)
      __hip_atomic_fetch_add(mycnt + s, 1u, __ATOMIC_RELAXED,
                             __HIP_MEMORY_SCOPE_AGENT);
  }
  pooled[(size_t)bb * 1024 + dir * H_ + hs + hh] = pm;
}

// ---------------- kernel 3: ht bf16 hi/lo -> rnn_out [t][b][dir*512+k] fp32 -------
__global__ __launch_bounds__(256) void finalize_k(
    const unsigned short* __restrict__ ht, float* __restrict__ rnn)
{
  const int t = blockIdx.x, dir = blockIdx.y;
  const int s = dir ? (T_ - 1 - t) : t;
  const char* base = (const char*)(ht + (size_t)(dir * T_ + s) * 32768);
  const int b = threadIdx.x >> 3, c = threadIdx.x & 7;
  float* __restrict__ dst = rnn + ((size_t)t * B_ + b) * 1024 + dir * H_;
  #pragma unroll
  for (int j = 0; j < 8; ++j) {
    const int k0 = (c * 8 + j) * 8;
    const unsigned off = (unsigned)((b * 1024 + k0 * 2) ^ ((b & 7) << 4));
    bf16x8 hi = *(const bf16x8*)(base + off);
    bf16x8 lo = *(const bf16x8*)(base + 32768 + off);
    float4 o0, o1;
    o0.x = bf2f((unsigned short)hi[0]) + bf2f((unsigned short)lo[0]);
    o0.y = bf2f((unsigned short)hi[1]) + bf2f((unsigned short)lo[1]);
    o0.z = bf2f((unsigned short)hi[2]) + bf2f((unsigned short)lo[2]);
    o0.w = bf2f((unsigned short)hi[3]) + bf2f((unsigned short)lo[3]);
    o1.x = bf2f((unsigned short)hi[4]) + bf2f((unsigned short)lo[4]);
    o1.y = bf2f((unsigned short)hi[5]) + bf2f((unsigned short)lo[5]);
    o1.z = bf2f((unsigned short)hi[6]) + bf2f((unsigned short)lo[6]);
    o1.w = bf2f((unsigned short)hi[7]) + bf2f((unsigned short)lo[7]);
    *(float4*)(dst + k0)     = o0;
    *(float4*)(dst + k0 + 4) = o1;
  }
}

// ---------------- kernel 4: logits = pooled @ W_out^T + b_out ---------------------
__global__ __launch_bounds__(64) void logits_k(
    const float* __restrict__ pooled, const float* __restrict__ Wout,
    const float* __restrict__ bout, float* __restrict__ out)
{
  const int b = blockIdx.x, lane = threadIdx.x;
  float acc[O_];
  #pragma unroll
  for (int o = 0; o < O_; ++o) acc[o] = 0.f;
  for (int k = lane; k < 2 * H_; k += 64) {
    const float pv = pooled[(size_t)b * 1024 + k];
    #pragma unroll
    for (int o = 0; o < O_; ++o) acc[o] += pv * Wout[(size_t)o * 1024 + k];
  }
  #pragma unroll
  for (int o = 0; o < O_; ++o) {
    float v = acc[o];
    #pragma unroll
    for (int off = 32; off > 0; off >>= 1) v += __shfl_down(v, off);
    if (lane == 0) out[b * O_ + o] = v + bout[o];
  }
}

extern "C" void kernel_launch(void* const* d_in, const int* in_sizes, int n_in,
                              void* d_out, int out_size, void* d_ws, size_t ws_size,
                              hipStream_t stream)
{
  const int*   tokens = (const int*)d_in[0];
  const float* embed  = (const float*)d_in[1];
  const float* Wihf   = (const float*)d_in[2];
  const float* Whhf   = (const float*)d_in[3];
  const float* bihf   = (const float*)d_in[4];
  const float* bhhf   = (const float*)d_in[5];
  const float* Wihb   = (const float*)d_in[6];
  const float* Whhb   = (const float*)d_in[7];
  const float* bihb   = (const float*)d_in[8];
  const float* bhhb   = (const float*)d_in[9];
  const float* Wout   = (const float*)d_in[10];
  const float* bout   = (const float*)d_in[11];
  float* out = (float*)d_out;

  char* ws = (char*)d_ws;
  const size_t XG_BYTES = (size_t)2 * T_ * 2048 * B_ * 2;       // 67,108,864
  const size_t HT_BYTES = (size_t)2 * T_ * 2 * B_ * H_ * 2;     // 33,554,432
  const size_t PL_BYTES = (size_t)B_ * 1024 * 4;                //    131,072
  const size_t CN_BYTES = (size_t)2 * T_ * 4;                   //      2,048
  const size_t EL_BYTES = 8 * 4;                                //         32
  if (ws_size < XG_BYTES + HT_BYTES + PL_BYTES + CN_BYTES + EL_BYTES) return;

  __hip_bfloat16* xg     = (__hip_bfloat16*)ws;
  unsigned short* ht     = (unsigned short*)(ws + XG_BYTES);
  float*          pooled = (float*)(ws + XG_BYTES + HT_BYTES);
  unsigned int*   cnt    = (unsigned int*)(ws + XG_BYTES + HT_BYTES + PL_BYTES);
  unsigned int*   elect  = (unsigned int*)(ws + XG_BYTES + HT_BYTES + PL_BYTES + CN_BYTES);

  (void)hipMemsetAsync(cnt, 0, CN_BYTES + EL_BYTES, stream);

  embed_xg_k<<<dim3(16, T_, 2), 256, 0, stream>>>(
      tokens, embed, Wihf, bihf, bhhf, Wihb, bihb, bhhb, xg);

  // 82,944 B dynamic LDS (64K h + 17,408 gp); 2x82944 > 160 KB -> 1 block/CU.
  const int rec_lds = 82944;
  (void)hipFuncSetAttribute((const void*)lstm_rec_k,
                            hipFuncAttributeMaxDynamicSharedMemorySize, rec_lds);
  lstm_rec_k<<<dim3(NBLK), THR, rec_lds, stream>>>(xg, Whhf, Whhb, ht, pooled,
                                                   cnt, elect);

  finalize_k<<<dim3(T_, 2), 256, 0, stream>>>(ht, out + B_ * O_);
  logits_k<<<dim3(B_), 64, 0, stream>>>(pooled, Wout, bout, out);
}

// Round 11
// 3286.863 us; speedup vs baseline: 3.1892x; 1.2105x over previous
//
#include <hip/hip_runtime.h>
#include <hip/hip_bf16.h>

#define B_ 32
#define T_ 256
#define E_ 300
#define EP_ 320      // padded K for MFMA (300 -> 320)
#define H_ 512
#define O_ 10
#define TEAM 32      // blocks per direction = CUs per XCD
#define THR 512      // threads per recurrence block
#define HPB 16       // h indices per block (512/32)
#define NBLK 512     // 2x oversubscribed so teams always fill

typedef __attribute__((ext_vector_type(8))) short bf16x8;
typedef __attribute__((ext_vector_type(4))) float f32x4;

__device__ __forceinline__ float bf2f(unsigned short u) {
  unsigned v = ((unsigned)u) << 16; float f; __builtin_memcpy(&f, &v, 4); return f;
}
__device__ __forceinline__ short f2bf(float x) {   // RNE bf16 (finite inputs)
  unsigned u; __builtin_memcpy(&u, &x, 4);
  unsigned r = u + 0x7fffu + ((u >> 16) & 1u);
  return (short)(r >> 16);
}

// ---------------- kernel 1a: token gather -> x bf16 hi/lo, K padded to 320 --------
__global__ __launch_bounds__(256) void xprep_k(
    const int* __restrict__ tokens, const float* __restrict__ embed,
    unsigned short* __restrict__ xb)   // [2 hilo][T][B][EP]
{
  const int t = blockIdx.x;
  __shared__ int tok_s[B_];
  const int tid = threadIdx.x;
  if (tid < B_) tok_s[tid] = tokens[tid * T_ + t];
  __syncthreads();
  const size_t plane = (size_t)T_ * B_ * EP_;
  unsigned short* hi = xb;
  unsigned short* lo = xb + plane;
  for (int i = tid; i < B_ * E_; i += 256) {
    const int b = i / E_, e = i - b * E_;
    const float v = embed[(size_t)tok_s[b] * E_ + e];
    const short h = f2bf(v);
    const short l = f2bf(v - bf2f((unsigned short)h));
    const size_t o = ((size_t)t * B_ + b) * EP_ + e;
    hi[o] = (unsigned short)h; lo[o] = (unsigned short)l;
  }
  for (int i = tid; i < B_ * (EP_ - E_); i += 256) {   // zero the K pad
    const int b = i / (EP_ - E_), e = E_ + (i - b * (EP_ - E_));
    const size_t o = ((size_t)t * B_ + b) * EP_ + e;
    hi[o] = 0; lo[o] = 0;
  }
}

// ---------------- kernel 1b: W_ih -> bf16 hi/lo planes, K padded ------------------
__global__ __launch_bounds__(320) void wprep_k(
    const float* __restrict__ Wf, const float* __restrict__ Wb,
    unsigned short* __restrict__ wp)   // [2 dir][2 hilo][2048][EP]
{
  const int row = blockIdx.x;          // 0..2047
  const int dir = blockIdx.y;
  const int e   = threadIdx.x;         // 0..319
  const float* __restrict__ W = dir ? Wb : Wf;
  short h = 0, l = 0;
  if (e < E_) {
    const float v = W[(size_t)row * E_ + e];
    h = f2bf(v);
    l = f2bf(v - bf2f((unsigned short)h));
  }
  const size_t hiB = ((size_t)(dir * 2 + 0)) * 2048 * EP_;
  const size_t loB = ((size_t)(dir * 2 + 1)) * 2048 * EP_;
  wp[hiB + (size_t)row * EP_ + e] = (unsigned short)h;
  wp[loB + (size_t)row * EP_ + e] = (unsigned short)l;
}

// ---------------- kernel 1c: xg = x@W_ih^T + b_ih + b_hh via MFMA -----------------
// r9-verified fragment conventions: A row m=l&15, k = kt*32 + (l>>4)*8 + j;
// B col (batch) = l&15, same k mapping; C col = l&15, row = (l>>4)*4 + r.
// 3 products (Whi*xhi + Wlo*xhi + Whi*xlo) = fp32-grade accuracy.
__global__ __launch_bounds__(256) void xg_mfma_k(
    const unsigned short* __restrict__ wp,   // [2][2][2048][EP]
    const unsigned short* __restrict__ xb,   // [2][T][B][EP]
    const float* __restrict__ bif, const float* __restrict__ bhf,
    const float* __restrict__ bib, const float* __restrict__ bhb,
    __hip_bfloat16* __restrict__ xg)         // [dir][t][2048][B] bf16
{
  const int rt  = blockIdx.x;    // 32 tiles of 64 rows
  const int t   = blockIdx.y;
  const int dir = blockIdx.z;
  const int tid = threadIdx.x;
  const int l = tid & 63, w = tid >> 6;      // 4 waves
  const int m = l & 15, q = l >> 4;
  const int rowb = rt * 64 + w * 16;         // this wave's 16 rows

  const float* __restrict__ bi = dir ? bib : bif;
  const float* __restrict__ bh = dir ? bhb : bhf;

  // A fragments (W rows) straight from L2
  bf16x8 ahi[10], alo[10];
  {
    const unsigned short* whi =
        wp + ((size_t)(dir * 2 + 0) * 2048 + rowb + m) * EP_ + q * 8;
    const unsigned short* wlo =
        wp + ((size_t)(dir * 2 + 1) * 2048 + rowb + m) * EP_ + q * 8;
    #pragma unroll
    for (int kt = 0; kt < 10; ++kt) {
      ahi[kt] = *(const bf16x8*)(whi + kt * 32);
      alo[kt] = *(const bf16x8*)(wlo + kt * 32);
    }
  }

  // B fragments (x) straight from L2/L3
  const size_t plane = (size_t)T_ * B_ * EP_;
  const unsigned short* xh0 = xb + ((size_t)t * B_ + m     ) * EP_ + q * 8;
  const unsigned short* xh1 = xb + ((size_t)t * B_ + m + 16) * EP_ + q * 8;

  f32x4 acc0 = {0.f, 0.f, 0.f, 0.f}, acc1 = {0.f, 0.f, 0.f, 0.f};
  #pragma unroll
  for (int kt = 0; kt < 10; ++kt) {
    bf16x8 b0h = *(const bf16x8*)(xh0 + kt * 32);
    bf16x8 b0l = *(const bf16x8*)(xh0 + plane + kt * 32);
    bf16x8 b1h = *(const bf16x8*)(xh1 + kt * 32);
    bf16x8 b1l = *(const bf16x8*)(xh1 + plane + kt * 32);
    acc0 = __builtin_amdgcn_mfma_f32_16x16x32_bf16(ahi[kt], b0h, acc0, 0, 0, 0);
    acc0 = __builtin_amdgcn_mfma_f32_16x16x32_bf16(alo[kt], b0h, acc0, 0, 0, 0);
    acc0 = __builtin_amdgcn_mfma_f32_16x16x32_bf16(ahi[kt], b0l, acc0, 0, 0, 0);
    acc1 = __builtin_amdgcn_mfma_f32_16x16x32_bf16(ahi[kt], b1h, acc1, 0, 0, 0);
    acc1 = __builtin_amdgcn_mfma_f32_16x16x32_bf16(alo[kt], b1h, acc1, 0, 0, 0);
    acc1 = __builtin_amdgcn_mfma_f32_16x16x32_bf16(ahi[kt], b1l, acc1, 0, 0, 0);
  }

  // epilogue: bias fold + bf16 store. C row = q*4+r, col = m (+16 for ntile1)
  const int r4 = rowb + q * 4;
  const float4 bi4 = *(const float4*)(bi + r4);
  const float4 bh4 = *(const float4*)(bh + r4);
  const float bias0 = bi4.x + bh4.x, bias1 = bi4.y + bh4.y;
  const float bias2 = bi4.z + bh4.z, bias3 = bi4.w + bh4.w;
  unsigned short* og =
      (unsigned short*)xg + ((size_t)(dir * T_ + t) * 2048 + r4) * B_;
  og[0 * B_ + m]      = (unsigned short)f2bf(acc0[0] + bias0);
  og[1 * B_ + m]      = (unsigned short)f2bf(acc0[1] + bias1);
  og[2 * B_ + m]      = (unsigned short)f2bf(acc0[2] + bias2);
  og[3 * B_ + m]      = (unsigned short)f2bf(acc0[3] + bias3);
  og[0 * B_ + m + 16] = (unsigned short)f2bf(acc1[0] + bias0);
  og[1 * B_ + m + 16] = (unsigned short)f2bf(acc1[1] + bias1);
  og[2 * B_ + m + 16] = (unsigned short)f2bf(acc1[2] + bias2);
  og[3 * B_ + m + 16] = (unsigned short)f2bf(acc1[3] + bias3);
}

// ---------------- kernel 2: XCD-local MFMA LSTM recurrence (r10, unchanged) -------
__device__ __forceinline__ float sigm(float x)    { return 1.f / (1.f + __expf(-x)); }
__device__ __forceinline__ float tanhfast(float x){ return 1.f - 2.f / (__expf(2.f * x) + 1.f); }

__global__ __launch_bounds__(THR) void lstm_rec_k(
    const __hip_bfloat16* __restrict__ xg,
    const float* __restrict__ Whf, const float* __restrict__ Whb,
    unsigned short* __restrict__ ht,   // [dir][s][hilo][32][512] bf16 pre-swizzled
    float* __restrict__ pooled,
    unsigned int* __restrict__ cnt, unsigned int* __restrict__ elect)
{
  unsigned xcd;
  asm volatile("s_getreg_b32 %0, hwreg(HW_REG_XCC_ID)" : "=s"(xcd));
  xcd &= 7u;

  __shared__ unsigned rank_s;
  if (threadIdx.x == 0)
    rank_s = __hip_atomic_fetch_add(&elect[xcd], 1u, __ATOMIC_RELAXED,
                                    __HIP_MEMORY_SCOPE_AGENT);
  __syncthreads();
  const unsigned rank = rank_s;
  if (xcd > 1u || rank >= TEAM) return;   // block-uniform exit (frees CU)
  const int dir = (int)xcd;

  const float* __restrict__ Wh = dir ? Whb : Whf;   // [2048][512]
  const int hs  = (int)rank * HPB;
  const int tid = threadIdx.x;
  const int l   = tid & 63;            // MFMA lane
  const int wid = tid >> 6;            // 8 waves
  const int g   = wid & 3;             // gate (i,f,g,o)
  const int kh  = wid >> 2;            // k-half (0: k<256, 1: k>=256)
  const int hh  = tid & 15, bb = tid >> 4;   // cell-update role (h idx, batch)

  extern __shared__ char lds[];        // [0,64K): h bf16 hi|lo ; [64K,+17408): gp
  float* gp = (float*)(lds + 65536);   // [8 slot][32 b][17] fp32 gate partials

  // ---- A-fragment preload: this wave's 16 W rows x its 256-k half, bf16 hi/lo ---
  bf16x8 ahi[8], alo[8];
  {
    const int m = l & 15, q = l >> 4;
    const float* wrow = Wh + (size_t)(g * H_ + hs + m) * H_ + kh * 256 + q * 8;
    #pragma unroll
    for (int kt = 0; kt < 8; ++kt) {
      const float* wp = wrow + kt * 32;
      #pragma unroll
      for (int j = 0; j < 8; ++j) {
        const float w = wp[j];
        const short hi = f2bf(w);
        ahi[kt][j] = hi;
        alo[kt][j] = f2bf(w - bf2f((unsigned short)hi));
      }
    }
  }

  const unsigned short* __restrict__ xgu = (const unsigned short*)xg;
  const size_t xco = ((size_t)hs + hh) * B_ + bb;   // cell xg offset (per gate +512*32)
  unsigned int* __restrict__ mycnt = cnt + (size_t)dir * T_;

  float c_st = 0.f, pm = 0.f;

  for (int s = 0; s < T_; ++s) {
    const int tt = dir ? (T_ - 1 - s) : s;
    const size_t xb = (size_t)(dir * T_ + tt) * 2048 * B_;
    // xg prefetch for cell update (hides under poll/stage)
    float x0 = bf2f(__builtin_nontemporal_load(xgu + xb + 0 * H_ * B_ + xco));
    float x1 = bf2f(__builtin_nontemporal_load(xgu + xb + 1 * H_ * B_ + xco));
    float x2 = bf2f(__builtin_nontemporal_load(xgu + xb + 2 * H_ * B_ + xco));
    float x3 = bf2f(__builtin_nontemporal_load(xgu + xb + 3 * H_ * B_ + xco));

    if (s > 0) {
      // barrier v2 poll: tid0 spins on one counter (agent-scope, L1-proof)
      if (tid == 0) {
        const unsigned int* cp = mycnt + (s - 1);
        unsigned v; int guard = 0;
        do { v = __hip_atomic_load(cp, __ATOMIC_RELAXED, __HIP_MEMORY_SCOPE_AGENT); }
        while (v < (unsigned)TEAM && ++guard < (1 << 22));
      }
      __syncthreads();
      // stage h(s-1) hi+lo (64 KB, already swizzled) linearly into LDS
      {
        const float4* src = (const float4*)(ht + (size_t)(dir * T_ + (s - 1)) * 32768);
        float4* dst = (float4*)lds;
        #pragma unroll
        for (int i = 0; i < 8; ++i)
          dst[tid + i * THR] = src[tid + i * THR];
      }
      __syncthreads();
      // MFMA: gates[g*16+hs.. ][b] partial over this k-half
      f32x4 acc0 = {0.f, 0.f, 0.f, 0.f}, acc1 = {0.f, 0.f, 0.f, 0.f};
      {
        const int n0 = l & 15;
        const int swz = (n0 & 7) << 4;
        const int kb = kh * 512 + (l >> 4) * 16;   // byte offset of this lane's k
        #pragma unroll
        for (int kt = 0; kt < 8; ++kt) {
          const int ko = kb + kt * 64;
          const char* p0 = lds + (((n0      ) * 1024 + ko) ^ swz);
          const char* p1 = lds + (((n0 + 16 ) * 1024 + ko) ^ swz);
          bf16x8 b0h = *(const bf16x8*)(p0);
          bf16x8 b0l = *(const bf16x8*)(p0 + 32768);
          bf16x8 b1h = *(const bf16x8*)(p1);
          bf16x8 b1l = *(const bf16x8*)(p1 + 32768);
          acc0 = __builtin_amdgcn_mfma_f32_16x16x32_bf16(ahi[kt], b0h, acc0, 0, 0, 0);
          acc0 = __builtin_amdgcn_mfma_f32_16x16x32_bf16(alo[kt], b0h, acc0, 0, 0, 0);
          acc0 = __builtin_amdgcn_mfma_f32_16x16x32_bf16(ahi[kt], b0l, acc0, 0, 0, 0);
          acc1 = __builtin_amdgcn_mfma_f32_16x16x32_bf16(ahi[kt], b1h, acc1, 0, 0, 0);
          acc1 = __builtin_amdgcn_mfma_f32_16x16x32_bf16(alo[kt], b1h, acc1, 0, 0, 0);
          acc1 = __builtin_amdgcn_mfma_f32_16x16x32_bf16(ahi[kt], b1l, acc1, 0, 0, 0);
        }
      }
      // write gate partials: C layout col=lane&15 (batch), row=(lane>>4)*4+r (h)
      {
        const int slot = (kh * 4 + g) * 32;
        const int rowb = (l >> 4) * 4;
        #pragma unroll
        for (int r = 0; r < 4; ++r) {
          gp[(slot + (l & 15)     ) * 17 + rowb + r] = acc0[r];
          gp[(slot + 16 + (l & 15)) * 17 + rowb + r] = acc1[r];
        }
      }
      __syncthreads();
    }

    // ---- cell update for (h = hs+hh, batch bb) ----
    float Gi = x0, Gf = x1, Gg = x2, Go = x3;
    if (s > 0) {
      Gi += gp[(0 * 32 + bb) * 17 + hh] + gp[(4 * 32 + bb) * 17 + hh];
      Gf += gp[(1 * 32 + bb) * 17 + hh] + gp[(5 * 32 + bb) * 17 + hh];
      Gg += gp[(2 * 32 + bb) * 17 + hh] + gp[(6 * 32 + bb) * 17 + hh];
      Go += gp[(3 * 32 + bb) * 17 + hh] + gp[(7 * 32 + bb) * 17 + hh];
    }
    c_st = sigm(Gf) * c_st + sigm(Gi) * tanhfast(Gg);
    const float h = sigm(Go) * tanhfast(c_st);
    pm = fmaxf(pm, h);
    // publish h as bf16 hi/lo, pre-swizzled [b][k] (byte ^= (b&7)<<4)
    {
      const short hi = f2bf(h);
      const short lo = f2bf(h - bf2f((unsigned short)hi));
      char* base = (char*)(ht + (size_t)(dir * T_ + s) * 32768);
      const unsigned off = (unsigned)((bb * 1024 + (hs + hh) * 2) ^ ((bb & 7) << 4));
      *(unsigned short*)(base + off)         = (unsigned short)hi;
      *(unsigned short*)(base + 32768 + off) = (unsigned short)lo;
    }
    asm volatile("s_waitcnt vmcnt(0)" ::: "memory");
    __syncthreads();
    if (tid == 0)
      __hip_atomic_fetch_add(mycnt + s, 1u, __ATOMIC_RELAXED,
                             __HIP_MEMORY_SCOPE_AGENT);
  }
  pooled[(size_t)bb * 1024 + dir * H_ + hs + hh] = pm;
}

// ---------------- kernel 3: ht bf16 hi/lo -> rnn_out [t][b][dir*512+k] fp32 -------
__global__ __launch_bounds__(256) void finalize_k(
    const unsigned short* __restrict__ ht, float* __restrict__ rnn)
{
  const int t = blockIdx.x, dir = blockIdx.y;
  const int s = dir ? (T_ - 1 - t) : t;
  const char* base = (const char*)(ht + (size_t)(dir * T_ + s) * 32768);
  const int b = threadIdx.x >> 3, c = threadIdx.x & 7;
  float* __restrict__ dst = rnn + ((size_t)t * B_ + b) * 1024 + dir * H_;
  #pragma unroll
  for (int j = 0; j < 8; ++j) {
    const int k0 = (c * 8 + j) * 8;
    const unsigned off = (unsigned)((b * 1024 + k0 * 2) ^ ((b & 7) << 4));
    bf16x8 hi = *(const bf16x8*)(base + off);
    bf16x8 lo = *(const bf16x8*)(base + 32768 + off);
    float4 o0, o1;
    o0.x = bf2f((unsigned short)hi[0]) + bf2f((unsigned short)lo[0]);
    o0.y = bf2f((unsigned short)hi[1]) + bf2f((unsigned short)lo[1]);
    o0.z = bf2f((unsigned short)hi[2]) + bf2f((unsigned short)lo[2]);
    o0.w = bf2f((unsigned short)hi[3]) + bf2f((unsigned short)lo[3]);
    o1.x = bf2f((unsigned short)hi[4]) + bf2f((unsigned short)lo[4]);
    o1.y = bf2f((unsigned short)hi[5]) + bf2f((unsigned short)lo[5]);
    o1.z = bf2f((unsigned short)hi[6]) + bf2f((unsigned short)lo[6]);
    o1.w = bf2f((unsigned short)hi[7]) + bf2f((unsigned short)lo[7]);
    *(float4*)(dst + k0)     = o0;
    *(float4*)(dst + k0 + 4) = o1;
  }
}

// ---------------- kernel 4: logits = pooled @ W_out^T + b_out ---------------------
__global__ __launch_bounds__(64) void logits_k(
    const float* __restrict__ pooled, const float* __restrict__ Wout,
    const float* __restrict__ bout, float* __restrict__ out)
{
  const int b = blockIdx.x, lane = threadIdx.x;
  float acc[O_];
  #pragma unroll
  for (int o = 0; o < O_; ++o) acc[o] = 0.f;
  for (int k = lane; k < 2 * H_; k += 64) {
    const float pv = pooled[(size_t)b * 1024 + k];
    #pragma unroll
    for (int o = 0; o < O_; ++o) acc[o] += pv * Wout[(size_t)o * 1024 + k];
  }
  #pragma unroll
  for (int o = 0; o < O_; ++o) {
    float v = acc[o];
    #pragma unroll
    for (int off = 32; off > 0; off >>= 1) v += __shfl_down(v, off);
    if (lane == 0) out[b * O_ + o] = v + bout[o];
  }
}

extern "C" void kernel_launch(void* const* d_in, const int* in_sizes, int n_in,
                              void* d_out, int out_size, void* d_ws, size_t ws_size,
                              hipStream_t stream)
{
  const int*   tokens = (const int*)d_in[0];
  const float* embed  = (const float*)d_in[1];
  const float* Wihf   = (const float*)d_in[2];
  const float* Whhf   = (const float*)d_in[3];
  const float* bihf   = (const float*)d_in[4];
  const float* bhhf   = (const float*)d_in[5];
  const float* Wihb   = (const float*)d_in[6];
  const float* Whhb   = (const float*)d_in[7];
  const float* bihb   = (const float*)d_in[8];
  const float* bhhb   = (const float*)d_in[9];
  const float* Wout   = (const float*)d_in[10];
  const float* bout   = (const float*)d_in[11];
  float* out = (float*)d_out;

  char* ws = (char*)d_ws;
  const size_t XG_BYTES = (size_t)2 * T_ * 2048 * B_ * 2;       // 67,108,864
  const size_t HT_BYTES = (size_t)2 * T_ * 2 * B_ * H_ * 2;     // 33,554,432
  const size_t PL_BYTES = (size_t)B_ * 1024 * 4;                //    131,072
  const size_t CN_BYTES = (size_t)2 * T_ * 4;                   //      2,048
  const size_t EL_BYTES = 8 * 4;                                //         32
  if (ws_size < XG_BYTES + HT_BYTES + PL_BYTES + CN_BYTES + EL_BYTES) return;

  __hip_bfloat16* xg     = (__hip_bfloat16*)ws;
  unsigned short* ht     = (unsigned short*)(ws + XG_BYTES);
  float*          pooled = (float*)(ws + XG_BYTES + HT_BYTES);
  unsigned int*   cnt    = (unsigned int*)(ws + XG_BYTES + HT_BYTES + PL_BYTES);
  unsigned int*   elect  = (unsigned int*)(ws + XG_BYTES + HT_BYTES + PL_BYTES + CN_BYTES);

  // xb (10,485,760 B) and wp (5,242,880 B) ALIAS the ht region: they are fully
  // consumed by xg_mfma_k before lstm_rec_k writes ht (stream-ordered).
  unsigned short* xb = (unsigned short*)(ws + XG_BYTES);
  unsigned short* wpre = (unsigned short*)(ws + XG_BYTES + (size_t)2 * T_ * B_ * EP_ * 2);

  (void)hipMemsetAsync(cnt, 0, CN_BYTES + EL_BYTES, stream);

  xprep_k<<<dim3(T_), 256, 0, stream>>>(tokens, embed, xb);
  wprep_k<<<dim3(2048, 2), 320, 0, stream>>>(Wihf, Wihb, wpre);
  xg_mfma_k<<<dim3(32, T_, 2), 256, 0, stream>>>(wpre, xb, bihf, bhhf, bihb, bhhb, xg);

  // 82,944 B dynamic LDS (64K h + 17,408 gp); 2x82944 > 160 KB -> 1 block/CU.
  const int rec_lds = 82944;
  (void)hipFuncSetAttribute((const void*)lstm_rec_k,
                            hipFuncAttributeMaxDynamicSharedMemorySize, rec_lds);
  lstm_rec_k<<<dim3(NBLK), THR, rec_lds, stream>>>(xg, Whhf, Whhb, ht, pooled,
                                                   cnt, elect);

  finalize_k<<<dim3(T_, 2), 256, 0, stream>>>(ht, out + B_ * O_);
  logits_k<<<dim3(B_), 64, 0, stream>>>(pooled, Wout, bout, out);
}